// Round 10
// baseline (480.925 us; speedup 1.0000x reference)
//
#include <hip/hip_runtime.h>
#include <hip/hip_bf16.h>
#include <math.h>

typedef unsigned short u16;
typedef __attribute__((ext_vector_type(8))) short short8;
typedef __attribute__((ext_vector_type(4))) float f32x4;

constexpr int Bc = 4, Tt = 2048, Dd = 768, Hh = 12, Hd = 64, Df = 3072;
constexpr int BT = Bc * Tt;  // 8192

__device__ __forceinline__ u16 f2b(float x) {
  __hip_bfloat16 h = __float2bfloat16(x);
  return *reinterpret_cast<u16*>(&h);
}
__device__ __forceinline__ float b2f(u16 v) {
  unsigned int u = ((unsigned int)v) << 16;
  return __builtin_bit_cast(float, u);
}
__device__ __forceinline__ float gelu_exact(float g) {
  return 0.5f * g * (1.0f + erff(g * 0.70710678118654752440f));
}
__device__ __forceinline__ void gload16(const void* g, void* l) {
  __builtin_amdgcn_global_load_lds(
      (const __attribute__((address_space(1))) unsigned int*)g,
      (__attribute__((address_space(3))) unsigned int*)l, 16, 0, 0);
}

// ---------------------------------------------------------------------------
// 32x32 transpose tile: in [R][C] fp32 -> out [C][R] bf16
// ---------------------------------------------------------------------------
__device__ __forceinline__ void tr_tile(const float* __restrict__ in,
                                        u16* __restrict__ out, int R, int C,
                                        int bx, int by, float* sh) {
  const int tx = threadIdx.x & 31, ty = threadIdx.x >> 5;
  const int r0 = by * 32, c0 = bx * 32;
#pragma unroll
  for (int i = 0; i < 4; ++i)
    sh[(ty + i * 8) * 33 + tx] = in[(size_t)(r0 + ty + i * 8) * C + c0 + tx];
  __syncthreads();
#pragma unroll
  for (int i = 0; i < 4; ++i)
    out[(size_t)(c0 + ty + i * 8) * R + r0 + tx] = f2b(sh[tx * 33 + ty + i * 8]);
}

// ---------------------------------------------------------------------------
// One fused prep kernel, dispatched by block range.
// ---------------------------------------------------------------------------
__global__ __launch_bounds__(256) void prep_all(
    const float* __restrict__ x, const float* __restrict__ Wq,
    const float* __restrict__ Wk, const float* __restrict__ Wv,
    const float* __restrict__ Wo, const float* __restrict__ W1,
    const float* __restrict__ W2, const float* __restrict__ bq,
    const float* __restrict__ bk, const float* __restrict__ bv,
    const int* __restrict__ mask, u16* __restrict__ xb,
    u16* __restrict__ wqkvT, u16* __restrict__ woT, u16* __restrict__ w1T,
    u16* __restrict__ w2T, float* __restrict__ biasc,
    unsigned int* __restrict__ mwords) {
  __shared__ float sh[32 * 33];
  const int s = blockIdx.x;
  if (s < 3072) {
    int i = (s * 256 + threadIdx.x) * 8;
    float4 a = *(const float4*)&x[i];
    float4 b = *(const float4*)&x[i + 4];
    u16 t[8] = {f2b(a.x), f2b(a.y), f2b(a.z), f2b(a.w),
                f2b(b.x), f2b(b.y), f2b(b.z), f2b(b.w)};
    *(uint4*)&xb[i] = *(uint4*)t;
  } else if (s < 3648) {
    int u = s - 3072; tr_tile(Wq, wqkvT, Dd, Dd, u % 24, u / 24, sh);
  } else if (s < 4224) {
    int u = s - 3648; tr_tile(Wk, wqkvT + 768 * Dd, Dd, Dd, u % 24, u / 24, sh);
  } else if (s < 4800) {
    int u = s - 4224; tr_tile(Wv, wqkvT + 1536 * Dd, Dd, Dd, u % 24, u / 24, sh);
  } else if (s < 5376) {
    int u = s - 4800; tr_tile(Wo, woT, Dd, Dd, u % 24, u / 24, sh);
  } else if (s < 7680) {
    int u = s - 5376; tr_tile(W1, w1T, Dd, Df, u % 96, u / 96, sh);
  } else if (s < 9984) {
    int u = s - 7680; tr_tile(W2, w2T, Df, Dd, u % 24, u / 24, sh);
  } else if (s < 9993) {
    int i = (s - 9984) * 256 + threadIdx.x;  // 0..2303
    biasc[i] = (i < 768) ? bq[i] : (i < 1536) ? bk[i - 768] : bv[i - 1536];
  } else {
    // pack mask bits: mwords[b*64 + w] bit j = mask[b*2048 + w*32 + j]
    const int id = threadIdx.x;  // 0..255
    const int b_ = id >> 6, kv0 = (id & 63) * 32;
    unsigned int wbits = 0u;
    for (int j = 0; j < 32; ++j)
      wbits |= (mask[b_ * Tt + kv0 + j] ? 1u : 0u) << j;
    mwords[id] = wbits;
  }
}

// ---------------------------------------------------------------------------
// bf16 MFMA NT GEMM, 128x128 tile, BK=32, 4 waves, 3-BUFFER counted-vmcnt
// pipeline: vmcnt(4) waits own stage(k) only (stage(k+1) floats), raw
// s_barrier, then stage(k+2) overlaps ds_read+MFMA of k.  setprio on MFMA.
// MODE 5: QKV fused (N=2304): Q split-head | K split-head | V^T [B,H,64,T]
// MODE 2: C0 bf16 h = x(add,f32) + acc + bias      (Wo, A gathered split-head)
// MODE 3: C0 bf16 gelu(acc + bias)                 (FF1)
// MODE 4: C0 fp32 addb(bf16 h) + acc + bias        (FF2)
// ---------------------------------------------------------------------------
template <int MODE>
__global__ __launch_bounds__(256) void mgemm(
    const u16* __restrict__ A, const u16* __restrict__ Bt,
    const float* __restrict__ bias, const float* __restrict__ add,
    const u16* __restrict__ addb, void* __restrict__ C0,
    void* __restrict__ C1, void* __restrict__ C2, int K, int N) {
  __shared__ __align__(16) u16 As[3][128 * 32];
  __shared__ __align__(16) u16 Bs[3][128 * 32];
  const int tid = threadIdx.x;
  const int lane = tid & 63, wv = tid >> 6;
  const int m0 = blockIdx.y * 128, n0 = blockIdx.x * 128;
  const int wm = (wv >> 1) * 64, wn = (wv & 1) * 64;

  f32x4 acc[4][4] = {};

#define MG_STAGE(k0_, bf_)                                                    \
  {                                                                           \
    _Pragma("unroll") for (int i_ = 0; i_ < 2; ++i_) {                        \
      const int idx_ = i_ * 256 + tid;                                        \
      const int row_ = idx_ >> 2;                                             \
      const int kc_ = (idx_ & 3) * 8;                                         \
      const u16* ga_;                                                         \
      if constexpr (MODE == 2) {                                              \
        const int m_ = m0 + row_, b_ = m_ >> 11, t_ = m_ & 2047;              \
        const int kk_ = (k0_) + kc_, hd_ = kk_ >> 6, d_ = kk_ & 63;           \
        ga_ = &A[(((size_t)(b_ * Hh + hd_) * Tt + t_) << 6) + d_];            \
      } else {                                                                \
        ga_ = &A[(size_t)(m0 + row_) * K + (k0_) + kc_];                      \
      }                                                                       \
      gload16(ga_, &As[bf_][idx_ * 8]);                                       \
      gload16(&Bt[(size_t)(n0 + row_) * K + (k0_) + kc_], &Bs[bf_][idx_ * 8]);\
    }                                                                         \
  }
#define FENCE() asm volatile("" ::: "memory")

  const int nsteps = K >> 5;
  MG_STAGE(0, 0);
  MG_STAGE(32, 1);

  for (int it = 0; it < nsteps; ++it) {
    if (it + 1 < nsteps)
      asm volatile("s_waitcnt vmcnt(4)" ::: "memory");  // own stage(it) done
    else
      asm volatile("s_waitcnt vmcnt(0)" ::: "memory");  // last: only stage(it)
    __builtin_amdgcn_s_barrier();
    FENCE();
    const int cur = it % 3;
    if (it + 2 < nsteps) {
      const int nb = (it + 2) % 3;
      MG_STAGE((it + 2) * 32, nb);  // overlaps compute below
    }
    short8 af[4], bfr[4];
#pragma unroll
    for (int i = 0; i < 4; ++i) {
      af[i] = *reinterpret_cast<const short8*>(
          &As[cur][(wm + i * 16 + (lane & 15)) * 32 + (lane >> 4) * 8]);
      bfr[i] = *reinterpret_cast<const short8*>(
          &Bs[cur][(wn + i * 16 + (lane & 15)) * 32 + (lane >> 4) * 8]);
    }
    __builtin_amdgcn_s_setprio(1);
#pragma unroll
    for (int i = 0; i < 4; ++i)
#pragma unroll
      for (int j = 0; j < 4; ++j)
        acc[i][j] = __builtin_amdgcn_mfma_f32_16x16x32_bf16(af[i], bfr[j],
                                                            acc[i][j], 0, 0, 0);
    __builtin_amdgcn_s_setprio(0);
  }
#undef MG_STAGE
#undef FENCE

  const int lr = (lane >> 4) * 4, lc = lane & 15;
#pragma unroll
  for (int i = 0; i < 4; ++i) {
    const int mbase = m0 + wm + i * 16 + lr;
#pragma unroll
    for (int j = 0; j < 4; ++j) {
      const int col = n0 + wn + j * 16 + lc;
      const float bvs = bias[col];
#pragma unroll
      for (int r = 0; r < 4; ++r) {
        const int m = mbase + r;
        float g = acc[i][j][r] + bvs;
        if constexpr (MODE == 5) {
          const int b = m >> 11, t = m & 2047;
          if (col < 768) {
            const int head = col >> 6, d = col & 63;
            ((u16*)C0)[(((size_t)(b * Hh + head) * Tt + t) << 6) + d] = f2b(g);
          } else if (col < 1536) {
            const int c = col - 768, head = c >> 6, d = c & 63;
            ((u16*)C1)[(((size_t)(b * Hh + head) * Tt + t) << 6) + d] = f2b(g);
          } else {
            const int c = col - 1536, head = c >> 6, d = c & 63;
            ((u16*)C2)[(((size_t)(b * Hh + head) * Hd + d) << 11) + t] = f2b(g);
          }
        } else if constexpr (MODE == 2) {
          g += add[(size_t)m * Dd + col];
          ((u16*)C0)[(size_t)m * Dd + col] = f2b(g);
        } else if constexpr (MODE == 3) {
          ((u16*)C0)[(size_t)m * N + col] = f2b(gelu_exact(g));
        } else {
          g += b2f(addb[(size_t)m * Dd + col]);
          ((float*)C0)[(size_t)m * Dd + col] = g;
        }
      }
    }
  }
}

// ---------------------------------------------------------------------------
// Fused attention v7 (unchanged from r9): counted-vmcnt pipeline, coalesced
// nontemporal attn stores, no-max softmax, packed mask bits.
// ---------------------------------------------------------------------------
__global__ __launch_bounds__(256) void attn_fused(
    const u16* __restrict__ qb, const u16* __restrict__ kb,
    const u16* __restrict__ vtb, const unsigned int* __restrict__ mwords,
    float* __restrict__ attn, u16* __restrict__ ctxb) {
  const int bh = blockIdx.y;
  const int b = bh / Hh;
  const int q0 = blockIdx.x * 64;
  const u16* Qg = qb + (size_t)bh * Tt * Hd;
  const u16* Kg = kb + (size_t)bh * Tt * Hd;
  const u16* Vg = vtb + (size_t)bh * Hd * Tt;  // [64][2048]
  float* attng = attn + (size_t)bh * Tt * Tt;
  u16* ctxg = ctxb + (size_t)bh * Tt * Hd;
  const unsigned int* mwp = mwords + b * 64;

  __shared__ __align__(16) u16 Ks[2][128 * 64];
  __shared__ __align__(16) u16 Vs[64 * 128];
  __shared__ __align__(16) float Pf[64 * 128];

  const int tid = threadIdx.x, lane = tid & 63, wv = tid >> 6;
  const int lc = lane & 15, lg = lane >> 4;
  const int ql = wv * 16 + lc;   // local q row this lane owns as MFMA col
  const int qsw = lc & 7;        // row-XOR for Pf granules

#define STAGE_K(t, bf)                                                       \
  {                                                                          \
    const int kv0_ = (t) * 128;                                              \
    _Pragma("unroll") for (int w_ = 0; w_ < 4; ++w_) {                       \
      const int p_ = w_ * 256 + tid;                                         \
      const int row_ = p_ >> 3, kc8_ = (p_ & 7) ^ (row_ & 7);                \
      gload16(Kg + (size_t)(kv0_ + row_) * Hd + kc8_ * 8, &Ks[bf][p_ * 8]);  \
    }                                                                        \
  }
#define STAGE_V(t)                                                           \
  {                                                                          \
    const int kv0_ = (t) * 128;                                              \
    _Pragma("unroll") for (int w_ = 0; w_ < 4; ++w_) {                       \
      const int p_ = w_ * 256 + tid;                                         \
      const int d_ = p_ >> 4, pc_ = (p_ & 15) ^ (d_ & 7);                    \
      gload16(Vg + (size_t)d_ * Tt + kv0_ + pc_ * 8, &Vs[p_ * 8]);           \
    }                                                                        \
  }
#define FENCE() asm volatile("" ::: "memory")

  // Q fragments once, register-resident (B-operand; one-time gather)
  short8 qf[2];
#pragma unroll
  for (int ks = 0; ks < 2; ++ks)
    qf[ks] = *(const short8*)&Qg[(size_t)(q0 + ql) * Hd + ks * 32 + lg * 8];

  float l = 0.f;

  // ---------------- pass 1: row sums l ----------------
  STAGE_K(0, 0);
  for (int t = 0; t < 16; ++t) {
    asm volatile("s_waitcnt vmcnt(0)" ::: "memory");
    __builtin_amdgcn_s_barrier();
    FENCE();
    const int bf = t & 1;
    if (t < 15) STAGE_K(t + 1, bf ^ 1);
    f32x4 s[8] = {};
#pragma unroll
    for (int ks = 0; ks < 2; ++ks) {
      const int ph = (ks * 4 + lg) ^ qsw;
#pragma unroll
      for (int i = 0; i < 8; ++i) {
        const short8 af = *(const short8*)&Ks[bf][(i * 16 + lc) * 64 + ph * 8];
        s[i] = __builtin_amdgcn_mfma_f32_16x16x32_bf16(af, qf[ks], s[i], 0, 0, 0);
      }
    }
    const uint4 mw4 = *(const uint4*)&mwp[t * 4];
    const unsigned int mwa[4] = {mw4.x, mw4.y, mw4.z, mw4.w};
    float ts = 0.f;
#pragma unroll
    for (int i = 0; i < 8; ++i) {
      const unsigned int w = mwa[i >> 1];
#pragma unroll
      for (int r = 0; r < 4; ++r) {
        const float bit = (float)((w >> ((i & 1) * 16 + lg * 4 + r)) & 1u);
        ts += __expf(s[i][r] * 0.125f) * bit;
      }
    }
    ts += __shfl_xor(ts, 16);
    ts += __shfl_xor(ts, 32);
    l += ts;
  }

  const float linv = 1.f / l;
  f32x4 cacc[4] = {};

  // barrier so pass-2 staging can't race pass-1's last reads of Ks[1]
  __builtin_amdgcn_s_barrier();
  FENCE();

  // ---------------- pass 2: P -> Pf -> ctx MFMA + floating nt store --------
  STAGE_K(0, 0);
  STAGE_V(0);
  for (int t = 0; t < 16; ++t) {
    const int kv0 = t * 128;
    const int bf = t & 1;
    if (t == 0)
      asm volatile("s_waitcnt vmcnt(0)" ::: "memory");
    else
      asm volatile("s_waitcnt vmcnt(8)" ::: "memory");  // stores_{t-1} float
    __builtin_amdgcn_s_barrier();
    FENCE();
    if (t < 15) STAGE_K(t + 1, bf ^ 1);  // overlaps QK^T below
    f32x4 s[8] = {};
#pragma unroll
    for (int ks = 0; ks < 2; ++ks) {
      const int ph = (ks * 4 + lg) ^ qsw;
#pragma unroll
      for (int i = 0; i < 8; ++i) {
        const short8 af = *(const short8*)&Ks[bf][(i * 16 + lc) * 64 + ph * 8];
        s[i] = __builtin_amdgcn_mfma_f32_16x16x32_bf16(af, qf[ks], s[i], 0, 0, 0);
      }
    }
    const uint4 mw4 = *(const uint4*)&mwp[t * 4];
    const unsigned int mwa[4] = {mw4.x, mw4.y, mw4.z, mw4.w};
#pragma unroll
    for (int i = 0; i < 8; ++i) {
      const unsigned int w = mwa[i >> 1];
      float pv[4];
#pragma unroll
      for (int r = 0; r < 4; ++r) {
        const float bit = (float)((w >> ((i & 1) * 16 + lg * 4 + r)) & 1u);
        pv[r] = __expf(s[i][r] * 0.125f) * bit * linv;
      }
      const int g = (i * 4 + lg) ^ qsw;  // granule swizzle
      *(f32x4*)&Pf[ql * 128 + g * 4] = *(f32x4*)pv;
    }
    // ctx += P @ V-tile (intra-wave Pf dep; compiler orders lgkm)
#pragma unroll
    for (int ks = 0; ks < 4; ++ks) {
      const int gA = (ks * 8 + lg * 2) ^ qsw;
      const int gB = (ks * 8 + lg * 2 + 1) ^ qsw;
      const f32x4 fA = *(const f32x4*)&Pf[ql * 128 + gA * 4];
      const f32x4 fB = *(const f32x4*)&Pf[ql * 128 + gB * 4];
      u16 pb[8] = {f2b(fA[0]), f2b(fA[1]), f2b(fA[2]), f2b(fA[3]),
                   f2b(fB[0]), f2b(fB[1]), f2b(fB[2]), f2b(fB[3])};
      const short8 pa = *(const short8*)pb;
#pragma unroll
      for (int j2 = 0; j2 < 4; ++j2) {
        const int d = j2 * 16 + lc;
        const short8 vb2 =
            *(const short8*)&Vs[d * 128 + (((ks * 4 + lg) ^ (d & 7))) * 8];
        cacc[j2] =
            __builtin_amdgcn_mfma_f32_16x16x32_bf16(pa, vb2, cacc[j2], 0, 0, 0);
      }
    }
    // all waves done reading Vs -> safe to restage V (no vmcnt drain here)
    __builtin_amdgcn_s_barrier();
    FENCE();
    if (t < 15) STAGE_V(t + 1);
    // cooperative coalesced NONTEMPORAL store (floats until vmcnt(8) later)
#pragma unroll
    for (int it = 0; it < 8; ++it) {
      const int row = wv * 16 + it * 2 + (lane >> 5);
      const int colg = lane & 31;
      const int g2 = colg ^ (row & 7);
      const f32x4 v = *(const f32x4*)&Pf[row * 128 + g2 * 4];
      __builtin_nontemporal_store(
          v, (f32x4*)&attng[(size_t)(q0 + row) * Tt + kv0 + colg * 4]);
    }
  }

  // ctx epilogue: bf16 split-head
#pragma unroll
  for (int j2 = 0; j2 < 4; ++j2)
#pragma unroll
    for (int r = 0; r < 4; ++r) {
      const int q = q0 + wv * 16 + lg * 4 + r;
      ctxg[(size_t)q * Hd + j2 * 16 + lc] = f2b(cacc[j2][r]);
    }
#undef STAGE_K
#undef STAGE_V
#undef FENCE
}

// ---------------------------------------------------------------------------
extern "C" void kernel_launch(void* const* d_in, const int* in_sizes, int n_in,
                              void* d_out, int out_size, void* d_ws,
                              size_t ws_size, hipStream_t stream) {
  const float* x = (const float*)d_in[0];
  const int* mask = (const int*)d_in[1];
  const float* Wq = (const float*)d_in[2];
  const float* bq = (const float*)d_in[3];
  const float* Wk = (const float*)d_in[4];
  const float* bk = (const float*)d_in[5];
  const float* Wv = (const float*)d_in[6];
  const float* bv = (const float*)d_in[7];
  const float* Wo = (const float*)d_in[8];
  const float* bo = (const float*)d_in[9];
  const float* W1 = (const float*)d_in[10];
  const float* b1 = (const float*)d_in[11];
  const float* W2 = (const float*)d_in[12];
  const float* b2 = (const float*)d_in[13];

  float* out = (float*)d_out;
  float* attn = out + (size_t)BT * Dd;

  char* w = (char*)d_ws;
  u16* xb = (u16*)w;      w += (size_t)BT * Dd * 2;
  u16* wqkvT = (u16*)w;   w += (size_t)Dd * 2304 * 2;
  u16* woT = (u16*)w;     w += (size_t)Dd * Dd * 2;
  u16* w1T = (u16*)w;     w += (size_t)Dd * Df * 2;
  u16* w2T = (u16*)w;     w += (size_t)Df * Dd * 2;
  float* biasc = (float*)w;            w += 2304 * 4;
  unsigned int* mwords = (unsigned int*)w; w += 256 * 4;
  u16* qb = (u16*)w;      w += (size_t)BT * Dd * 2;
  u16* kb = (u16*)w;      w += (size_t)BT * Dd * 2;
  u16* vtb = (u16*)w;     w += (size_t)BT * Dd * 2;
  u16* ctxb = (u16*)w;    w += (size_t)BT * Dd * 2;
  u16* ff1b = (u16*)w;    w += (size_t)BT * Df * 2;
  u16* hb = vtb;  // overlays vtb (dead after attn_fused)

  dim3 blk(256);

  // all prep in one launch
  prep_all<<<dim3(9994), blk, 0, stream>>>(x, Wq, Wk, Wv, Wo, W1, W2, bq, bk,
                                           bv, mask, xb, wqkvT, woT, w1T, w2T,
                                           biasc, mwords);

  // fused QKV projection (N = 2304)
  mgemm<5><<<dim3(18, 64), blk, 0, stream>>>(xb, wqkvT, biasc, nullptr, nullptr,
                                             qb, kb, vtb, Dd, 2304);

  // fused attention: attn (written once, coalesced, nt, floating) + ctx
  attn_fused<<<dim3(32, 48), blk, 0, stream>>>(qb, kb, vtb, mwords, attn, ctxb);

  // h(bf16) = x + ctx@Wo + bo
  mgemm<2><<<dim3(6, 64), blk, 0, stream>>>(ctxb, woT, bo, x, nullptr, hb,
                                            nullptr, nullptr, Dd, Dd);

  // ff1 = gelu(h@W1 + b1) bf16
  mgemm<3><<<dim3(24, 64), blk, 0, stream>>>(hb, w1T, b1, nullptr, nullptr,
                                             ff1b, nullptr, nullptr, Dd, Df);

  // out = h + ff1@W2 + b2   (residual from bf16 h)
  mgemm<4><<<dim3(6, 64), blk, 0, stream>>>(ff1b, w2T, b2, nullptr, hb, out,
                                            nullptr, nullptr, Df, Dd);
}

// Round 11
// 474.253 us; speedup vs baseline: 1.0141x; 1.0141x over previous
//
#include <hip/hip_runtime.h>
#include <hip/hip_bf16.h>
#include <math.h>

typedef unsigned short u16;
typedef __attribute__((ext_vector_type(8))) short short8;
typedef __attribute__((ext_vector_type(4))) float f32x4;

constexpr int Bc = 4, Tt = 2048, Dd = 768, Hh = 12, Hd = 64, Df = 3072;
constexpr int BT = Bc * Tt;  // 8192

__device__ __forceinline__ u16 f2b(float x) {
  __hip_bfloat16 h = __float2bfloat16(x);
  return *reinterpret_cast<u16*>(&h);
}
__device__ __forceinline__ float b2f(u16 v) {
  unsigned int u = ((unsigned int)v) << 16;
  return __builtin_bit_cast(float, u);
}
__device__ __forceinline__ float gelu_exact(float g) {
  return 0.5f * g * (1.0f + erff(g * 0.70710678118654752440f));
}
__device__ __forceinline__ void gload16(const void* g, void* l) {
  __builtin_amdgcn_global_load_lds(
      (const __attribute__((address_space(1))) unsigned int*)g,
      (__attribute__((address_space(3))) unsigned int*)l, 16, 0, 0);
}

// ---------------------------------------------------------------------------
// 32x32 transpose tile: in [R][C] fp32 -> out [C][R] bf16
// ---------------------------------------------------------------------------
__device__ __forceinline__ void tr_tile(const float* __restrict__ in,
                                        u16* __restrict__ out, int R, int C,
                                        int bx, int by, float* sh) {
  const int tx = threadIdx.x & 31, ty = threadIdx.x >> 5;
  const int r0 = by * 32, c0 = bx * 32;
#pragma unroll
  for (int i = 0; i < 4; ++i)
    sh[(ty + i * 8) * 33 + tx] = in[(size_t)(r0 + ty + i * 8) * C + c0 + tx];
  __syncthreads();
#pragma unroll
  for (int i = 0; i < 4; ++i)
    out[(size_t)(c0 + ty + i * 8) * R + r0 + tx] = f2b(sh[tx * 33 + ty + i * 8]);
}

// ---------------------------------------------------------------------------
// One fused prep kernel, dispatched by block range.
// ---------------------------------------------------------------------------
__global__ __launch_bounds__(256) void prep_all(
    const float* __restrict__ x, const float* __restrict__ Wq,
    const float* __restrict__ Wk, const float* __restrict__ Wv,
    const float* __restrict__ Wo, const float* __restrict__ W1,
    const float* __restrict__ W2, const float* __restrict__ bq,
    const float* __restrict__ bk, const float* __restrict__ bv,
    const int* __restrict__ mask, u16* __restrict__ xb,
    u16* __restrict__ wqkvT, u16* __restrict__ woT, u16* __restrict__ w1T,
    u16* __restrict__ w2T, float* __restrict__ biasc,
    unsigned int* __restrict__ mwords) {
  __shared__ float sh[32 * 33];
  const int s = blockIdx.x;
  if (s < 3072) {
    int i = (s * 256 + threadIdx.x) * 8;
    float4 a = *(const float4*)&x[i];
    float4 b = *(const float4*)&x[i + 4];
    u16 t[8] = {f2b(a.x), f2b(a.y), f2b(a.z), f2b(a.w),
                f2b(b.x), f2b(b.y), f2b(b.z), f2b(b.w)};
    *(uint4*)&xb[i] = *(uint4*)t;
  } else if (s < 3648) {
    int u = s - 3072; tr_tile(Wq, wqkvT, Dd, Dd, u % 24, u / 24, sh);
  } else if (s < 4224) {
    int u = s - 3648; tr_tile(Wk, wqkvT + 768 * Dd, Dd, Dd, u % 24, u / 24, sh);
  } else if (s < 4800) {
    int u = s - 4224; tr_tile(Wv, wqkvT + 1536 * Dd, Dd, Dd, u % 24, u / 24, sh);
  } else if (s < 5376) {
    int u = s - 4800; tr_tile(Wo, woT, Dd, Dd, u % 24, u / 24, sh);
  } else if (s < 7680) {
    int u = s - 5376; tr_tile(W1, w1T, Dd, Df, u % 96, u / 96, sh);
  } else if (s < 9984) {
    int u = s - 7680; tr_tile(W2, w2T, Df, Dd, u % 24, u / 24, sh);
  } else if (s < 9993) {
    int i = (s - 9984) * 256 + threadIdx.x;  // 0..2303
    biasc[i] = (i < 768) ? bq[i] : (i < 1536) ? bk[i - 768] : bv[i - 1536];
  } else {
    // pack mask bits: mwords[b*64 + w] bit j = mask[b*2048 + w*32 + j]
    const int id = threadIdx.x;  // 0..255
    const int b_ = id >> 6, kv0 = (id & 63) * 32;
    unsigned int wbits = 0u;
    for (int j = 0; j < 32; ++j)
      wbits |= (mask[b_ * Tt + kv0 + j] ? 1u : 0u) << j;
    mwords[id] = wbits;
  }
}

// ---------------------------------------------------------------------------
// bf16 MFMA NT GEMM, 128x128 tile, BK=32, 4 waves, double-buffered LDS
// (r9 structure - best measured): stage k+1 before compute of k, single
// __syncthreads per K-step.
// MODE 5: QKV fused (N=2304): Q split-head | K split-head | V^T [B,H,64,T]
// MODE 2: C0 bf16 h = x(add,f32) + acc + bias      (Wo, A gathered split-head)
// MODE 3: C0 bf16 gelu(acc + bias)                 (FF1)
// MODE 4: C0 fp32 addb(bf16 h) + acc + bias        (FF2)
// ---------------------------------------------------------------------------
template <int MODE>
__global__ __launch_bounds__(256) void mgemm(
    const u16* __restrict__ A, const u16* __restrict__ Bt,
    const float* __restrict__ bias, const float* __restrict__ add,
    const u16* __restrict__ addb, void* __restrict__ C0,
    void* __restrict__ C1, void* __restrict__ C2, int K, int N) {
  __shared__ __align__(16) u16 As[2][128 * 32];
  __shared__ __align__(16) u16 Bs[2][128 * 32];
  const int tid = threadIdx.x;
  const int lane = tid & 63, wv = tid >> 6;
  const int m0 = blockIdx.y * 128, n0 = blockIdx.x * 128;
  const int wm = (wv >> 1) * 64, wn = (wv & 1) * 64;

  f32x4 acc[4][4] = {};

#define MG_STAGE(k0_, bf_)                                                    \
  {                                                                           \
    _Pragma("unroll") for (int i_ = 0; i_ < 2; ++i_) {                        \
      const int idx_ = i_ * 256 + tid;                                        \
      const int row_ = idx_ >> 2;                                             \
      const int kc_ = (idx_ & 3) * 8;                                         \
      const u16* ga_;                                                         \
      if constexpr (MODE == 2) {                                              \
        const int m_ = m0 + row_, b_ = m_ >> 11, t_ = m_ & 2047;              \
        const int kk_ = (k0_) + kc_, hd_ = kk_ >> 6, d_ = kk_ & 63;           \
        ga_ = &A[(((size_t)(b_ * Hh + hd_) * Tt + t_) << 6) + d_];            \
      } else {                                                                \
        ga_ = &A[(size_t)(m0 + row_) * K + (k0_) + kc_];                      \
      }                                                                       \
      gload16(ga_, &As[bf_][idx_ * 8]);                                       \
      gload16(&Bt[(size_t)(n0 + row_) * K + (k0_) + kc_], &Bs[bf_][idx_ * 8]);\
    }                                                                         \
  }

  MG_STAGE(0, 0);
  __syncthreads();

  int it = 0;
  for (int k0 = 0; k0 < K; k0 += 32, ++it) {
    const int cur = it & 1;
    if (k0 + 32 < K) MG_STAGE(k0 + 32, cur ^ 1);  // overlaps compute below
    short8 af[4], bfr[4];
#pragma unroll
    for (int i = 0; i < 4; ++i) {
      af[i] = *reinterpret_cast<const short8*>(
          &As[cur][(wm + i * 16 + (lane & 15)) * 32 + (lane >> 4) * 8]);
      bfr[i] = *reinterpret_cast<const short8*>(
          &Bs[cur][(wn + i * 16 + (lane & 15)) * 32 + (lane >> 4) * 8]);
    }
#pragma unroll
    for (int i = 0; i < 4; ++i)
#pragma unroll
      for (int j = 0; j < 4; ++j)
        acc[i][j] = __builtin_amdgcn_mfma_f32_16x16x32_bf16(af[i], bfr[j],
                                                            acc[i][j], 0, 0, 0);
    __syncthreads();  // drains next-tile staging (overlapped) + LDS reads
  }
#undef MG_STAGE

  const int lr = (lane >> 4) * 4, lc = lane & 15;
#pragma unroll
  for (int i = 0; i < 4; ++i) {
    const int mbase = m0 + wm + i * 16 + lr;
#pragma unroll
    for (int j = 0; j < 4; ++j) {
      const int col = n0 + wn + j * 16 + lc;
      const float bvs = bias[col];
#pragma unroll
      for (int r = 0; r < 4; ++r) {
        const int m = mbase + r;
        float g = acc[i][j][r] + bvs;
        if constexpr (MODE == 5) {
          const int b = m >> 11, t = m & 2047;
          if (col < 768) {
            const int head = col >> 6, d = col & 63;
            ((u16*)C0)[(((size_t)(b * Hh + head) * Tt + t) << 6) + d] = f2b(g);
          } else if (col < 1536) {
            const int c = col - 768, head = c >> 6, d = c & 63;
            ((u16*)C1)[(((size_t)(b * Hh + head) * Tt + t) << 6) + d] = f2b(g);
          } else {
            const int c = col - 1536, head = c >> 6, d = c & 63;
            ((u16*)C2)[(((size_t)(b * Hh + head) * Hd + d) << 11) + t] = f2b(g);
          }
        } else if constexpr (MODE == 2) {
          g += add[(size_t)m * Dd + col];
          ((u16*)C0)[(size_t)m * Dd + col] = f2b(g);
        } else if constexpr (MODE == 3) {
          ((u16*)C0)[(size_t)m * N + col] = f2b(gelu_exact(g));
        } else {
          g += b2f(addb[(size_t)m * Dd + col]);
          ((float*)C0)[(size_t)m * Dd + col] = g;
        }
      }
    }
  }
}

// ---------------------------------------------------------------------------
// Fused attention v8: bf16 P tile (r5/r6-verified layout) + BOTH K and V
// double-buffered + ONE barrier per tile.  Per pass-2 tile:
//   vmcnt(8) [K_t,V_t ready; stores_{t-1} float] -> s_barrier
//   -> stage K_{t+1},V_{t+1} (dbuf; latency hidden under full tile body)
//   -> QK^T -> exp -> Ps(bf16, own-wave rows, no barrier needed)
//   -> PV MFMA (reads Ps directly as A-frags) -> coalesced nt store-out
//      (bf16->f32 convert on the fly).
// LDS: Ks 2x16K + Vs 2x16K + Ps 16K = 80KB -> 2 blocks/CU.
// attn output now bf16-rounded (<=0.004 abs; threshold 0.11).
// ---------------------------------------------------------------------------
__global__ __launch_bounds__(256) void attn_fused(
    const u16* __restrict__ qb, const u16* __restrict__ kb,
    const u16* __restrict__ vtb, const unsigned int* __restrict__ mwords,
    float* __restrict__ attn, u16* __restrict__ ctxb) {
  const int bh = blockIdx.y;
  const int b = bh / Hh;
  const int q0 = blockIdx.x * 64;
  const u16* Qg = qb + (size_t)bh * Tt * Hd;
  const u16* Kg = kb + (size_t)bh * Tt * Hd;
  const u16* Vg = vtb + (size_t)bh * Hd * Tt;  // [64][2048]
  float* attng = attn + (size_t)bh * Tt * Tt;
  u16* ctxg = ctxb + (size_t)bh * Tt * Hd;
  const unsigned int* mwp = mwords + b * 64;

  __shared__ __align__(16) u16 Ks[2][128 * 64];
  __shared__ __align__(16) u16 Vs[2][64 * 128];
  __shared__ __align__(16) u16 Ps[64 * 128];

  const int tid = threadIdx.x, lane = tid & 63, wv = tid >> 6;
  const int lc = lane & 15, lg = lane >> 4;
  const int ql = wv * 16 + lc;   // local q row this lane owns as MFMA col
  const int qsw = lc & 7;        // row-XOR swizzle

#define STAGE_K(t, bf)                                                       \
  {                                                                          \
    const int kv0_ = (t) * 128;                                              \
    _Pragma("unroll") for (int w_ = 0; w_ < 4; ++w_) {                       \
      const int p_ = w_ * 256 + tid;                                         \
      const int row_ = p_ >> 3, kc8_ = (p_ & 7) ^ (row_ & 7);                \
      gload16(Kg + (size_t)(kv0_ + row_) * Hd + kc8_ * 8, &Ks[bf][p_ * 8]);  \
    }                                                                        \
  }
#define STAGE_V(t, bf)                                                       \
  {                                                                          \
    const int kv0_ = (t) * 128;                                              \
    _Pragma("unroll") for (int w_ = 0; w_ < 4; ++w_) {                       \
      const int p_ = w_ * 256 + tid;                                         \
      const int d_ = p_ >> 4, pc_ = (p_ & 15) ^ (d_ & 7);                    \
      gload16(Vg + (size_t)d_ * Tt + kv0_ + pc_ * 8, &Vs[bf][p_ * 8]);       \
    }                                                                        \
  }
#define FENCE() asm volatile("" ::: "memory")

  // Q fragments once, register-resident (B-operand; one-time gather)
  short8 qf[2];
#pragma unroll
  for (int ks = 0; ks < 2; ++ks)
    qf[ks] = *(const short8*)&Qg[(size_t)(q0 + ql) * Hd + ks * 32 + lg * 8];

  float l = 0.f;

  // ---------------- pass 1: row sums l (K dbuf, 1 barrier/tile) ----------
  STAGE_K(0, 0);
  for (int t = 0; t < 16; ++t) {
    asm volatile("s_waitcnt vmcnt(0)" ::: "memory");
    __builtin_amdgcn_s_barrier();
    FENCE();
    const int bf = t & 1;
    if (t < 15) STAGE_K(t + 1, bf ^ 1);
    f32x4 s[8] = {};
#pragma unroll
    for (int ks = 0; ks < 2; ++ks) {
      const int ph = (ks * 4 + lg) ^ qsw;
#pragma unroll
      for (int i = 0; i < 8; ++i) {
        const short8 af = *(const short8*)&Ks[bf][(i * 16 + lc) * 64 + ph * 8];
        s[i] = __builtin_amdgcn_mfma_f32_16x16x32_bf16(af, qf[ks], s[i], 0, 0, 0);
      }
    }
    const uint4 mw4 = *(const uint4*)&mwp[t * 4];
    const unsigned int mwa[4] = {mw4.x, mw4.y, mw4.z, mw4.w};
    float ts = 0.f;
#pragma unroll
    for (int i = 0; i < 8; ++i) {
      const unsigned int w = mwa[i >> 1];
#pragma unroll
      for (int r = 0; r < 4; ++r) {
        const float bit = (float)((w >> ((i & 1) * 16 + lg * 4 + r)) & 1u);
        ts += __expf(s[i][r] * 0.125f) * bit;
      }
    }
    ts += __shfl_xor(ts, 16);
    ts += __shfl_xor(ts, 32);
    l += ts;
  }

  const float linv = 1.f / l;
  f32x4 cacc[4] = {};

  // barrier so pass-2 staging can't race pass-1's last reads of Ks[1]
  __builtin_amdgcn_s_barrier();
  FENCE();

  // ---------------- pass 2: 1 barrier/tile, K+V dbuf, floating nt stores --
  STAGE_K(0, 0);
  STAGE_V(0, 0);
  for (int t = 0; t < 16; ++t) {
    const int kv0 = t * 128;
    const int bf = t & 1;
    if (t == 0)
      asm volatile("s_waitcnt vmcnt(0)" ::: "memory");
    else
      asm volatile("s_waitcnt vmcnt(8)" ::: "memory");  // K_t,V_t ready; stores float
    __builtin_amdgcn_s_barrier();
    FENCE();
    if (t < 15) {
      STAGE_K(t + 1, bf ^ 1);  // latency hidden under full tile body
      STAGE_V(t + 1, bf ^ 1);
    }
    f32x4 s[8] = {};
#pragma unroll
    for (int ks = 0; ks < 2; ++ks) {
      const int ph = (ks * 4 + lg) ^ qsw;
#pragma unroll
      for (int i = 0; i < 8; ++i) {
        const short8 af = *(const short8*)&Ks[bf][(i * 16 + lc) * 64 + ph * 8];
        s[i] = __builtin_amdgcn_mfma_f32_16x16x32_bf16(af, qf[ks], s[i], 0, 0, 0);
      }
    }
    const uint4 mw4 = *(const uint4*)&mwp[t * 4];
    const unsigned int mwa[4] = {mw4.x, mw4.y, mw4.z, mw4.w};
#pragma unroll
    for (int i = 0; i < 8; ++i) {
      const unsigned int w = mwa[i >> 1];
      u16 pb[4];
#pragma unroll
      for (int r = 0; r < 4; ++r) {
        const float bit = (float)((w >> ((i & 1) * 16 + lg * 4 + r)) & 1u);
        pb[r] = f2b(__expf(s[i][r] * 0.125f) * bit * linv);
      }
      const int chunk = i * 2 + (lg >> 1);
      const int ph2 = chunk ^ qsw;
      *(uint2*)&Ps[ql * 128 + ph2 * 8 + (lg & 1) * 4] = *(uint2*)pb;
    }
    // ctx += P @ V-tile (Ps rows own-wave: intra-wave dep, no barrier)
#pragma unroll
    for (int ks = 0; ks < 4; ++ks) {
      const short8 pa =
          *(const short8*)&Ps[ql * 128 + ((ks * 4 + lg) ^ qsw) * 8];
#pragma unroll
      for (int j2 = 0; j2 < 4; ++j2) {
        const int d = j2 * 16 + lc;
        const short8 vb2 =
            *(const short8*)&Vs[bf][d * 128 + (((ks * 4 + lg) ^ (d & 7))) * 8];
        cacc[j2] =
            __builtin_amdgcn_mfma_f32_16x16x32_bf16(pa, vb2, cacc[j2], 0, 0, 0);
      }
    }
    // coalesced NT store-out (bf16 -> f32), floats until next vmcnt(8)
#pragma unroll
    for (int it2 = 0; it2 < 8; ++it2) {
      const int row = wv * 16 + it2 * 2 + (lane >> 5);
      const int colg = lane & 31;
      const int chunk = colg >> 1, half = colg & 1;
      const uint2 pr = *(const uint2*)&Ps[row * 128 +
                                          (chunk ^ (row & 7)) * 8 + half * 4];
      f32x4 v;
      v[0] = b2f((u16)(pr.x & 0xffffu));
      v[1] = b2f((u16)(pr.x >> 16));
      v[2] = b2f((u16)(pr.y & 0xffffu));
      v[3] = b2f((u16)(pr.y >> 16));
      __builtin_nontemporal_store(
          v, (f32x4*)&attng[(size_t)(q0 + row) * Tt + kv0 + colg * 4]);
    }
  }

  // ctx epilogue: bf16 split-head
#pragma unroll
  for (int j2 = 0; j2 < 4; ++j2)
#pragma unroll
    for (int r = 0; r < 4; ++r) {
      const int q = q0 + wv * 16 + lg * 4 + r;
      ctxg[(size_t)q * Hd + j2 * 16 + lc] = f2b(cacc[j2][r]);
    }
#undef STAGE_K
#undef STAGE_V
#undef FENCE
}

// ---------------------------------------------------------------------------
extern "C" void kernel_launch(void* const* d_in, const int* in_sizes, int n_in,
                              void* d_out, int out_size, void* d_ws,
                              size_t ws_size, hipStream_t stream) {
  const float* x = (const float*)d_in[0];
  const int* mask = (const int*)d_in[1];
  const float* Wq = (const float*)d_in[2];
  const float* bq = (const float*)d_in[3];
  const float* Wk = (const float*)d_in[4];
  const float* bk = (const float*)d_in[5];
  const float* Wv = (const float*)d_in[6];
  const float* bv = (const float*)d_in[7];
  const float* Wo = (const float*)d_in[8];
  const float* bo = (const float*)d_in[9];
  const float* W1 = (const float*)d_in[10];
  const float* b1 = (const float*)d_in[11];
  const float* W2 = (const float*)d_in[12];
  const float* b2 = (const float*)d_in[13];

  float* out = (float*)d_out;
  float* attn = out + (size_t)BT * Dd;

  char* w = (char*)d_ws;
  u16* xb = (u16*)w;      w += (size_t)BT * Dd * 2;
  u16* wqkvT = (u16*)w;   w += (size_t)Dd * 2304 * 2;
  u16* woT = (u16*)w;     w += (size_t)Dd * Dd * 2;
  u16* w1T = (u16*)w;     w += (size_t)Dd * Df * 2;
  u16* w2T = (u16*)w;     w += (size_t)Df * Dd * 2;
  float* biasc = (float*)w;            w += 2304 * 4;
  unsigned int* mwords = (unsigned int*)w; w += 256 * 4;
  u16* qb = (u16*)w;      w += (size_t)BT * Dd * 2;
  u16* kb = (u16*)w;      w += (size_t)BT * Dd * 2;
  u16* vtb = (u16*)w;     w += (size_t)BT * Dd * 2;
  u16* ctxb = (u16*)w;    w += (size_t)BT * Dd * 2;
  u16* ff1b = (u16*)w;    w += (size_t)BT * Df * 2;
  u16* hb = vtb;  // overlays vtb (dead after attn_fused)

  dim3 blk(256);

  // all prep in one launch
  prep_all<<<dim3(9994), blk, 0, stream>>>(x, Wq, Wk, Wv, Wo, W1, W2, bq, bk,
                                           bv, mask, xb, wqkvT, woT, w1T, w2T,
                                           biasc, mwords);

  // fused QKV projection (N = 2304)
  mgemm<5><<<dim3(18, 64), blk, 0, stream>>>(xb, wqkvT, biasc, nullptr, nullptr,
                                             qb, kb, vtb, Dd, 2304);

  // fused attention: attn (written once, coalesced, nt, floating) + ctx
  attn_fused<<<dim3(32, 48), blk, 0, stream>>>(qb, kb, vtb, mwords, attn, ctxb);

  // h(bf16) = x + ctx@Wo + bo
  mgemm<2><<<dim3(6, 64), blk, 0, stream>>>(ctxb, woT, bo, x, nullptr, hb,
                                            nullptr, nullptr, Dd, Dd);

  // ff1 = gelu(h@W1 + b1) bf16
  mgemm<3><<<dim3(24, 64), blk, 0, stream>>>(hb, w1T, b1, nullptr, nullptr,
                                             ff1b, nullptr, nullptr, Dd, Df);

  // out = h + ff1@W2 + b2   (residual from bf16 h)
  mgemm<4><<<dim3(6, 64), blk, 0, stream>>>(ff1b, w2T, b2, nullptr, hb, out,
                                            nullptr, nullptr, Df, Dd);
}